// Round 11
// baseline (213.659 us; speedup 1.0000x reference)
//
#include <hip/hip_runtime.h>

#define NN 16
constexpr int BB = 32, CIN = 64, HH = 112, WW = 112;
constexpr int HWC = HH * WW;          // 12544
constexpr int COUT = 128, HW2 = 56 * 56;
constexpr int NE = 64;
constexpr int NQ = HWC / 4;           // 3136 float4 pixels per image
constexpr int QPB = 64;               // pixel-quads per conv block
constexpr int BPI = NQ / QPB;         // 49 conv blocks per image (exact)
constexpr int PF4 = COUT * HW2 / 4;   // 100352 float4 per batch
constexpr int SBPB = 28;              // scale blocks per batch (28*3584 = PF4)
constexpr int JPT = 14;               // float4 iters per scale thread
constexpr int PREF = 6;               // register prefetch depth

// ---- Kernel 1: 1x1 conv + segment scatter; LAST block per image runs the
// tiny graph network (threadfence-reduction pattern, deterministic order). ----
__global__ __launch_bounds__(256) void k_conv_seg(
    const float* __restrict__ Bfor, const int* __restrict__ seg,
    const float* __restrict__ convw,
    const int* __restrict__ src, const int* __restrict__ dst,
    const float* __restrict__ convb,
    const float* __restrict__ W1, const float* __restrict__ b1,
    const float* __restrict__ W2, const float* __restrict__ b2,
    const float* __restrict__ fcw, const float* __restrict__ fcb,
    float* __restrict__ part, float* __restrict__ G, int* __restrict__ cnt)
{
    __shared__ float w[CIN];
    __shared__ float ps[4 * QPB * 5];   // [cg][quad][px], stride-5 bank skew
    __shared__ float acc[8 * 80];       // [replica][node*5+st], bank-skewed
    const int tid = threadIdx.x;
    const int b   = blockIdx.x / BPI;
    const int blk = blockIdx.x % BPI;
    const int cg  = tid >> 6;           // channel group == wave id
    const int l   = tid & 63;           // quad lane

    if (tid < CIN) w[tid] = convw[tid];
    for (int i = tid; i < 8 * 80; i += 256) acc[i] = 0.f;
    __syncthreads();

    const int p = (blk * QPB + l) * 4;
    const float* base = Bfor + (size_t)b * CIN * HWC + (size_t)(cg * 16) * HWC + p;

    float4 s = make_float4(0.f, 0.f, 0.f, 0.f);
    #pragma unroll
    for (int cc = 0; cc < 16; ++cc) {
        const float4 v = *reinterpret_cast<const float4*>(base + (size_t)cc * HWC);
        const float wc = w[cg * 16 + cc];
        s.x = fmaf(v.x, wc, s.x);
        s.y = fmaf(v.y, wc, s.y);
        s.z = fmaf(v.z, wc, s.z);
        s.w = fmaf(v.w, wc, s.w);
    }
    ps[cg * 320 + l * 5 + 0] = s.x;
    ps[cg * 320 + l * 5 + 1] = s.y;
    ps[cg * 320 + l * 5 + 2] = s.z;
    ps[cg * 320 + l * 5 + 3] = s.w;
    __syncthreads();

    if (tid < 64) {
        float r0 = 0.f, r1 = 0.f, r2 = 0.f, r3 = 0.f;
        #pragma unroll
        for (int g = 0; g < 4; ++g) {
            r0 += ps[g * 320 + tid * 5 + 0];
            r1 += ps[g * 320 + tid * 5 + 1];
            r2 += ps[g * 320 + tid * 5 + 2];
            r3 += ps[g * 320 + tid * 5 + 3];
        }
        const int pp = (blk * QPB + tid) * 4;
        const int4 sg = *reinterpret_cast<const int4*>(seg + (size_t)b * HWC + pp);
        const float row  = (float)(pp / WW);   // WW%4==0 -> all 4 px same row
        const float col0 = (float)(pp % WW);
        const int k = tid & 7;                 // replica
        atomicAdd(&acc[k * 80 + sg.x * 5 + 0], row);
        atomicAdd(&acc[k * 80 + sg.x * 5 + 1], col0);
        atomicAdd(&acc[k * 80 + sg.x * 5 + 2], r0);
        atomicAdd(&acc[k * 80 + sg.x * 5 + 3], 1.f);
        atomicAdd(&acc[k * 80 + sg.y * 5 + 0], row);
        atomicAdd(&acc[k * 80 + sg.y * 5 + 1], col0 + 1.f);
        atomicAdd(&acc[k * 80 + sg.y * 5 + 2], r1);
        atomicAdd(&acc[k * 80 + sg.y * 5 + 3], 1.f);
        atomicAdd(&acc[k * 80 + sg.z * 5 + 0], row);
        atomicAdd(&acc[k * 80 + sg.z * 5 + 1], col0 + 2.f);
        atomicAdd(&acc[k * 80 + sg.z * 5 + 2], r2);
        atomicAdd(&acc[k * 80 + sg.z * 5 + 3], 1.f);
        atomicAdd(&acc[k * 80 + sg.w * 5 + 0], row);
        atomicAdd(&acc[k * 80 + sg.w * 5 + 1], col0 + 3.f);
        atomicAdd(&acc[k * 80 + sg.w * 5 + 2], r3);
        atomicAdd(&acc[k * 80 + sg.w * 5 + 3], 1.f);
    }
    __syncthreads();

    if (tid < NN * 4) {
        const int node = tid >> 2, st = tid & 3;
        float v = 0.f;
        #pragma unroll
        for (int k = 0; k < 8; ++k) v += acc[k * 80 + node * 5 + st];
        part[((b * BPI + blk) * NN + node) * 4 + st] = v;
    }

    // ---- last-block detection (CUDA threadFenceReduction pattern) ----
    __shared__ int lastFlag;
    __threadfence();
    __syncthreads();
    if (tid == 0) lastFlag = (atomicAdd(&cnt[b], 1) == BPI - 1);
    __syncthreads();
    if (!lastFlag) return;
    __threadfence();   // acquire: see all blocks' part[] writes

    // ======== graph network for image b (only 1 block per image) ========
    __shared__ float X[NN][4];
    __shared__ float A[NN][NN];
    __shared__ float nrm[NN];
    __shared__ float h1s[NN][32];
    __shared__ float agg[NN][32];
    __shared__ float pred[4][64];
    __shared__ float gpart[2][COUT];

    {   // reduce 49 partials: 4 chunks x <=13, coalesced
        const int id = tid & 63, chunk = tid >> 6;
        float v = 0.f;
        const int k0 = chunk * 13, k1e = (k0 + 13 < BPI) ? k0 + 13 : BPI;
        for (int k = k0; k < k1e; ++k) v += part[(size_t)(b * BPI + k) * 64 + id];
        pred[chunk][id] = v;
    }
    for (int i = tid; i < NN * NN; i += 256) ((float*)A)[i] = 0.f;
    __syncthreads();

    if (tid < 64) {
        const int node = tid >> 2, st = tid & 3;
        X[node][st] = pred[0][tid] + pred[1][tid] + pred[2][tid] + pred[3][tid];
    }
    __syncthreads();

    if (tid < NN) {        // raw sums -> features (conv bias folded in)
        const float cnt_ = X[tid][3];
        const float cs   = fmaxf(cnt_, 1.f);
        X[tid][0] = X[tid][0] / cs;
        X[tid][1] = X[tid][1] / cs;
        X[tid][2] = (X[tid][2] + cnt_ * convb[0]) / cs;
    }
    __syncthreads();

    if (tid < 2) {         // normalize cols 2,3 (mean, std ddof=1)
        const int c = 2 + tid;
        float mu = 0.f;
        for (int i = 0; i < NN; ++i) mu += X[i][c];
        mu *= (1.f / NN);
        float var = 0.f;
        for (int i = 0; i < NN; ++i) { const float d = X[i][c] - mu; var = fmaf(d, d, var); }
        var *= (1.f / (NN - 1));
        const float inv = 1.f / (sqrtf(var) + 1.f);
        for (int i = 0; i < NN; ++i) X[i][c] = (X[i][c] - mu) * inv;
    }
    if (tid >= 64 && tid < 64 + NE) {   // adjacency (idempotent set-to-1)
        const int e = tid - 64;
        const int sE = src[b * NE + e], dE = dst[b * NE + e];
        A[sE][dE] = 1.f;
        A[dE][sE] = 1.f;
    }
    __syncthreads();

    if (tid < NN) {
        float rs = 0.f;
        for (int j = 0; j < NN; ++j) rs += A[tid][j];
        nrm[tid] = 1.f / sqrtf(fmaxf(rs, 1.f));
    }
    __syncthreads();

    if (tid < NN * 4) {    // agg1 (16x4)
        const int i = tid >> 2, k = tid & 3;
        float sA = 0.f;
        for (int j = 0; j < NN; ++j) sA = fmaf(A[i][j] * nrm[j], X[j][k], sA);
        agg[i][k] = sA;
    }
    __syncthreads();

    for (int t = tid; t < NN * 32; t += 256) {   // h1 (16x32)
        const int i = t >> 5, f = t & 31;
        float sA = 0.f;
        #pragma unroll
        for (int k = 0; k < 4; ++k) sA = fmaf(agg[i][k], W1[k * 32 + f], sA);
        h1s[i][f] = fmaxf(fmaf(nrm[i], sA, b1[f]), 0.f);
    }
    __syncthreads();

    for (int t = tid; t < NN * 32; t += 256) {   // agg2 (16x32)
        const int i = t >> 5, k = t & 31;
        float sA = 0.f;
        for (int j = 0; j < NN; ++j) sA = fmaf(A[i][j] * nrm[j], h1s[j][k], sA);
        agg[i][k] = sA;
    }
    __syncthreads();

    {   // h2 + FC, i-range split across 2 half-blocks
        const int f = tid & 127, half = tid >> 7;
        float g = 0.f;
        const float bf = b2[f];
        for (int i = half * 8; i < half * 8 + 8; ++i) {
            float sA = 0.f;
            #pragma unroll
            for (int k = 0; k < 32; ++k) sA = fmaf(agg[i][k], W2[k * COUT + f], sA);
            g = fmaf(fcw[i], fmaxf(fmaf(nrm[i], sA, bf), 0.f), g);
        }
        gpart[half][f] = g;
    }
    __syncthreads();
    if (tid < COUT) G[b * COUT + tid] = gpart[0][tid] + gpart[1][tid] + fcb[0];
}

// ---- Kernel 2: pure-stream scale with rolling register prefetch ----
__global__ __launch_bounds__(256) void k_scale(
    const float* __restrict__ Bfon, const float* __restrict__ Gg,
    float* __restrict__ out)
{
    const int b    = blockIdx.x / SBPB;
    const int blkb = blockIdx.x % SBPB;
    const int tid  = threadIdx.x;
    const int w0   = blkb * (JPT * 256);   // contiguous window in [0, PF4)

    __shared__ float Gs[COUT];
    const float4* bf4 = reinterpret_cast<const float4*>(Bfon) + (size_t)b * PF4;
    float4*       ob4 = reinterpret_cast<float4*>(out)        + (size_t)b * PF4;

    float4 r[JPT];
    #pragma unroll
    for (int j = 0; j < PREF; ++j) r[j] = bf4[w0 + j * 256 + tid];

    if (tid < COUT) Gs[tid] = Gg[b * COUT + tid];
    __syncthreads();

    #pragma unroll
    for (int j = 0; j < JPT; ++j) {
        if (j + PREF < JPT) r[j + PREF] = bf4[w0 + (j + PREF) * 256 + tid];
        const int t = w0 + j * 256 + tid;
        const float g = Gs[t / (HW2 / 4)];   // 784 float4 per (b,c) plane
        ob4[t] = make_float4(r[j].x * g, r[j].y * g, r[j].z * g, r[j].w * g);
    }
}

extern "C" void kernel_launch(void* const* d_in, const int* in_sizes, int n_in,
                              void* d_out, int out_size, void* d_ws, size_t ws_size,
                              hipStream_t stream)
{
    const float* Bfor  = (const float*)d_in[0];
    const float* Bfon  = (const float*)d_in[1];
    const int*   seg   = (const int*)d_in[2];
    const int*   src   = (const int*)d_in[3];
    const int*   dst   = (const int*)d_in[4];
    const float* convw = (const float*)d_in[5];
    const float* convb = (const float*)d_in[6];
    const float* W1    = (const float*)d_in[7];
    const float* b1    = (const float*)d_in[8];
    const float* W2    = (const float*)d_in[9];
    const float* b2    = (const float*)d_in[10];
    const float* fcw   = (const float*)d_in[11];
    const float* fcb   = (const float*)d_in[12];

    float* part = (float*)d_ws;                  // 1568*64 floats = 401 KB
    float* G    = part + BB * BPI * NN * 4;      // 32*128 floats
    int*   cnt  = (int*)(G + BB * COUT);         // 32 ints

    hipMemsetAsync(cnt, 0, BB * sizeof(int), stream);
    k_conv_seg<<<BB * BPI, 256, 0, stream>>>(Bfor, seg, convw, src, dst, convb,
                                             W1, b1, W2, b2, fcw, fcb,
                                             part, G, cnt);
    k_scale<<<BB * SBPB, 256, 0, stream>>>(Bfon, G, (float*)d_out);
}

// Round 12
// 99.985 us; speedup vs baseline: 2.1369x; 2.1369x over previous
//
#include <hip/hip_runtime.h>

#define NN 16
constexpr int BB = 32, CIN = 64, HH = 112, WW = 112;
constexpr int HWC = HH * WW;          // 12544
constexpr int COUT = 128, HW2 = 56 * 56;
constexpr int NE = 64;
constexpr int QPB = 64;               // pixel-quads per conv unit
constexpr int BPI = 49;               // conv units per image (49*64*4 = 12544)
constexpr int UNITS = BB * BPI;       // 1568
constexpr int PF4 = COUT * HW2 / 4;   // 100352 float4 per image
constexpr int NCONV = 896;            // conv-role blocks
constexpr int GRID = 1024;            // == 4 blocks/CU * 256 CU (co-resident)
constexpr int CHUNKS = BB * COUT;     // 4096 scale chunks; chunk = (image,channel)
constexpr int CF4 = HW2 / 4;          // 784 float4 per chunk

__global__ __launch_bounds__(256, 4) void k_fused(
    const float* __restrict__ Bfor, const int* __restrict__ seg,
    const float* __restrict__ convw,
    const int* __restrict__ src, const int* __restrict__ dst,
    const float* __restrict__ convb,
    const float* __restrict__ W1, const float* __restrict__ b1,
    const float* __restrict__ W2, const float* __restrict__ b2,
    const float* __restrict__ fcw, const float* __restrict__ fcb,
    const float* __restrict__ Bfon, float* __restrict__ out,
    float* __restrict__ accg, float* __restrict__ G,
    int* __restrict__ ucnt, int* __restrict__ gflag, int* __restrict__ wq)
{
    __shared__ float w[CIN];
    __shared__ float ps[4 * QPB * 5];   // [cg][quad][px], stride-5 bank skew
    __shared__ float acc8[8 * 80];      // [replica][node*5+st], bank-skewed
    __shared__ float X[NN][4];
    __shared__ float A[NN][NN];
    __shared__ float nrm[NN];
    __shared__ float h1s[NN][32];
    __shared__ float agg[NN][32];
    __shared__ float gpart[2][COUT];
    __shared__ int done_sh, chunk_sh;

    const int tid = threadIdx.x;
    const int bid = blockIdx.x;
    const int cg  = tid >> 6;           // channel group == wave id
    const int l   = tid & 63;           // quad lane

    // =================== conv role: up to 2 units (R3 structure) ===========
    if (bid < NCONV) {
        if (tid < CIN) w[tid] = convw[tid];
        for (int pass = 0; pass < 2; ++pass) {
            const int u = bid + pass * NCONV;
            if (u >= UNITS) break;                 // block-uniform
            const int b   = u / BPI;
            const int blk = u % BPI;

            for (int i = tid; i < 8 * 80; i += 256) acc8[i] = 0.f;
            __syncthreads();

            const int p = (blk * QPB + l) * 4;
            const float* base = Bfor + (size_t)b * CIN * HWC
                                     + (size_t)(cg * 16) * HWC + p;
            float4 s = make_float4(0.f, 0.f, 0.f, 0.f);
            #pragma unroll
            for (int cc = 0; cc < 16; ++cc) {
                const float4 v = *reinterpret_cast<const float4*>(base + (size_t)cc * HWC);
                const float wc = w[cg * 16 + cc];
                s.x = fmaf(v.x, wc, s.x);
                s.y = fmaf(v.y, wc, s.y);
                s.z = fmaf(v.z, wc, s.z);
                s.w = fmaf(v.w, wc, s.w);
            }
            ps[cg * 320 + l * 5 + 0] = s.x;
            ps[cg * 320 + l * 5 + 1] = s.y;
            ps[cg * 320 + l * 5 + 2] = s.z;
            ps[cg * 320 + l * 5 + 3] = s.w;
            __syncthreads();

            if (tid < 64) {
                float r0 = 0.f, r1 = 0.f, r2 = 0.f, r3 = 0.f;
                #pragma unroll
                for (int g2 = 0; g2 < 4; ++g2) {
                    r0 += ps[g2 * 320 + tid * 5 + 0];
                    r1 += ps[g2 * 320 + tid * 5 + 1];
                    r2 += ps[g2 * 320 + tid * 5 + 2];
                    r3 += ps[g2 * 320 + tid * 5 + 3];
                }
                const int pp = (blk * QPB + tid) * 4;
                const int4 sg = *reinterpret_cast<const int4*>(seg + (size_t)b * HWC + pp);
                const float row  = (float)(pp / WW);   // WW%4==0
                const float col0 = (float)(pp % WW);
                const int k = tid & 7;                 // replica
                atomicAdd(&acc8[k * 80 + sg.x * 5 + 0], row);
                atomicAdd(&acc8[k * 80 + sg.x * 5 + 1], col0);
                atomicAdd(&acc8[k * 80 + sg.x * 5 + 2], r0);
                atomicAdd(&acc8[k * 80 + sg.x * 5 + 3], 1.f);
                atomicAdd(&acc8[k * 80 + sg.y * 5 + 0], row);
                atomicAdd(&acc8[k * 80 + sg.y * 5 + 1], col0 + 1.f);
                atomicAdd(&acc8[k * 80 + sg.y * 5 + 2], r1);
                atomicAdd(&acc8[k * 80 + sg.y * 5 + 3], 1.f);
                atomicAdd(&acc8[k * 80 + sg.z * 5 + 0], row);
                atomicAdd(&acc8[k * 80 + sg.z * 5 + 1], col0 + 2.f);
                atomicAdd(&acc8[k * 80 + sg.z * 5 + 2], r2);
                atomicAdd(&acc8[k * 80 + sg.z * 5 + 3], 1.f);
                atomicAdd(&acc8[k * 80 + sg.w * 5 + 0], row);
                atomicAdd(&acc8[k * 80 + sg.w * 5 + 1], col0 + 3.f);
                atomicAdd(&acc8[k * 80 + sg.w * 5 + 2], r3);
                atomicAdd(&acc8[k * 80 + sg.w * 5 + 3], 1.f);
            }
            __syncthreads();

            if (tid < 64) {   // 8-replica reduce -> coherent global accumulate
                float v = 0.f;
                #pragma unroll
                for (int k = 0; k < 8; ++k)
                    v += acc8[k * 80 + (tid >> 2) * 5 + (tid & 3)];
                atomicAdd(&accg[b * 64 + tid], v);
            }
            // wave 0's value-atomics must COMPLETE before the count publishes
            asm volatile("s_waitcnt vmcnt(0)" ::: "memory");
            if (tid == 0) done_sh = (atomicAdd(&ucnt[b], 1) == BPI - 1) ? 1 : 0;
            __syncthreads();

            if (done_sh) {   // ==== this block completes image b: run graph ====
                if (tid < 64)    // coherent read of the accumulated stats
                    X[tid >> 2][tid & 3] = atomicAdd(&accg[b * 64 + tid], 0.f);
                ((float*)A)[tid] = 0.f;    // 256 entries, 256 threads
                __syncthreads();

                if (tid < NN) {  // raw sums -> features (conv bias folded in)
                    const float cnt = X[tid][3];
                    const float cs  = fmaxf(cnt, 1.f);
                    X[tid][0] = X[tid][0] / cs;
                    X[tid][1] = X[tid][1] / cs;
                    X[tid][2] = (X[tid][2] + cnt * convb[0]) / cs;
                }
                __syncthreads();

                if (tid < 2) {   // normalize cols 2,3 (mean, std ddof=1)
                    const int c = 2 + tid;
                    float mu = 0.f;
                    for (int i = 0; i < NN; ++i) mu += X[i][c];
                    mu *= (1.f / NN);
                    float var = 0.f;
                    for (int i = 0; i < NN; ++i) { const float d = X[i][c] - mu; var = fmaf(d, d, var); }
                    var *= (1.f / (NN - 1));
                    const float inv = 1.f / (sqrtf(var) + 1.f);
                    for (int i = 0; i < NN; ++i) X[i][c] = (X[i][c] - mu) * inv;
                }
                if (tid >= 64 && tid < 64 + NE) {   // adjacency (idempotent)
                    const int e = tid - 64;
                    const int sE = src[b * NE + e], dE = dst[b * NE + e];
                    A[sE][dE] = 1.f;
                    A[dE][sE] = 1.f;
                }
                __syncthreads();

                if (tid < NN) {
                    float rs = 0.f;
                    for (int j = 0; j < NN; ++j) rs += A[tid][j];
                    nrm[tid] = 1.f / sqrtf(fmaxf(rs, 1.f));
                }
                __syncthreads();

                if (tid < NN * 4) {   // agg1 (16x4)
                    const int i = tid >> 2, k = tid & 3;
                    float sA = 0.f;
                    for (int j = 0; j < NN; ++j) sA = fmaf(A[i][j] * nrm[j], X[j][k], sA);
                    agg[i][k] = sA;
                }
                __syncthreads();

                for (int t = tid; t < NN * 32; t += 256) {   // h1 (16x32)
                    const int i = t >> 5, f = t & 31;
                    float sA = 0.f;
                    #pragma unroll
                    for (int k = 0; k < 4; ++k) sA = fmaf(agg[i][k], W1[k * 32 + f], sA);
                    h1s[i][f] = fmaxf(fmaf(nrm[i], sA, b1[f]), 0.f);
                }
                __syncthreads();

                for (int t = tid; t < NN * 32; t += 256) {   // agg2 (16x32)
                    const int i = t >> 5, k = t & 31;
                    float sA = 0.f;
                    for (int j = 0; j < NN; ++j) sA = fmaf(A[i][j] * nrm[j], h1s[j][k], sA);
                    agg[i][k] = sA;
                }
                __syncthreads();

                {   // h2 + FC, i-range split across 2 half-blocks
                    const int f = tid & 127, half = tid >> 7;
                    float g = 0.f;
                    const float bf = b2[f];
                    for (int i = half * 8; i < half * 8 + 8; ++i) {
                        float sA = 0.f;
                        #pragma unroll
                        for (int k = 0; k < 32; ++k) sA = fmaf(agg[i][k], W2[k * COUT + f], sA);
                        g = fmaf(fcw[i], fmaxf(fmaf(nrm[i], sA, bf), 0.f), g);
                    }
                    gpart[half][f] = g;
                }
                __syncthreads();
                if (tid < COUT)   // coherent publish of G, then ready flag
                    atomicExch(&G[b * COUT + tid], gpart[0][tid] + gpart[1][tid] + fcb[0]);
                asm volatile("s_waitcnt vmcnt(0)" ::: "memory");
                __syncthreads();   // all publishing waves past their vmcnt
                if (tid == 0) atomicExch(&gflag[b], 1);
            }
            __syncthreads();
        }
    }

    // ============ scale: dynamic image-major work queue (all blocks) ========
    const float4* bf4 = reinterpret_cast<const float4*>(Bfon);
    float4*       ob4 = reinterpret_cast<float4*>(out);
    for (;;) {
        if (tid == 0) chunk_sh = atomicAdd(wq, 1);
        __syncthreads();
        const int c = chunk_sh;
        if (c >= CHUNKS) break;                    // block-uniform
        const int i = c >> 7, j = c & 127;         // image, channel
        if (tid == 0) {
            while (atomicAdd(&gflag[i], 0) == 0) __builtin_amdgcn_s_sleep(8);
        }
        __syncthreads();
        asm volatile("" ::: "memory");             // no hoisting above the flag
        const float g = G[i * COUT + j];           // first-touch-after-ready
        const size_t t0 = (size_t)i * PF4 + (size_t)j * CF4;
        const float4 v0 = bf4[t0 + tid];
        const float4 v1 = bf4[t0 + 256 + tid];
        const float4 v2 = bf4[t0 + 512 + tid];
        ob4[t0 + tid]       = make_float4(v0.x * g, v0.y * g, v0.z * g, v0.w * g);
        ob4[t0 + 256 + tid] = make_float4(v1.x * g, v1.y * g, v1.z * g, v1.w * g);
        ob4[t0 + 512 + tid] = make_float4(v2.x * g, v2.y * g, v2.z * g, v2.w * g);
        if (tid < CF4 - 768) {                     // 784 = 3*256 + 16
            const float4 v3 = bf4[t0 + 768 + tid];
            ob4[t0 + 768 + tid] = make_float4(v3.x * g, v3.y * g, v3.z * g, v3.w * g);
        }
        __syncthreads();
    }
}

extern "C" void kernel_launch(void* const* d_in, const int* in_sizes, int n_in,
                              void* d_out, int out_size, void* d_ws, size_t ws_size,
                              hipStream_t stream)
{
    const float* Bfor  = (const float*)d_in[0];
    const float* Bfon  = (const float*)d_in[1];
    const int*   seg   = (const int*)d_in[2];
    const int*   src   = (const int*)d_in[3];
    const int*   dst   = (const int*)d_in[4];
    const float* convw = (const float*)d_in[5];
    const float* convb = (const float*)d_in[6];
    const float* W1    = (const float*)d_in[7];
    const float* b1    = (const float*)d_in[8];
    const float* W2    = (const float*)d_in[9];
    const float* b2    = (const float*)d_in[10];
    const float* fcw   = (const float*)d_in[11];
    const float* fcb   = (const float*)d_in[12];

    float* accg  = (float*)d_ws;                 // 32*64 floats  (zeroed)
    float* G     = accg + BB * 64;               // 32*128 floats (fully overwritten)
    int*   ints  = (int*)(G + BB * COUT);        // ucnt[32] | gflag[32] | wq[1]
    int*   ucnt  = ints;
    int*   gflag = ints + BB;
    int*   wq    = ints + 2 * BB;

    hipMemsetAsync(accg, 0, BB * 64 * sizeof(float), stream);
    hipMemsetAsync(ints, 0, (2 * BB + 1) * sizeof(int), stream);
    k_fused<<<GRID, 256, 0, stream>>>(Bfor, seg, convw, src, dst, convb,
                                      W1, b1, W2, b2, fcw, fcb,
                                      Bfon, (float*)d_out,
                                      accg, G, ucnt, gflag, wq);
}

// Round 13
// 57.536 us; speedup vs baseline: 3.7135x; 1.7378x over previous
//
#include <hip/hip_runtime.h>

#define NN 16
constexpr int BB = 32, CIN = 64, HH = 112, WW = 112;
constexpr int HWC = HH * WW;          // 12544
constexpr int COUT = 128, HW2 = 56 * 56;
constexpr int NE = 64;
constexpr int NQ = HWC / 4;           // 3136 float4 pixels per image
constexpr int QPB = 64;               // pixel-quads per conv block
constexpr int BPI = NQ / QPB;         // 49 conv blocks per image (exact)
constexpr int PF4 = COUT * HW2 / 4;   // 100352 float4 per batch
constexpr int SBPB = 28;              // scale blocks per batch (28*3584 = PF4)
constexpr int JPT = 14;               // float4 iters per scale thread
constexpr int PREF = 6;               // register prefetch depth

// ---- Kernel 1: 1x1 conv (R3 structure) + coherent-atomic stats accumulate;
// the LAST block of each image runs the tiny graph inline (R12-validated
// pattern: value-atomics -> vmcnt(0) -> counter atomic -> graph tail). ----
__global__ __launch_bounds__(256) void k_conv_seg(
    const float* __restrict__ Bfor, const int* __restrict__ seg,
    const float* __restrict__ convw,
    const int* __restrict__ src, const int* __restrict__ dst,
    const float* __restrict__ convb,
    const float* __restrict__ W1, const float* __restrict__ b1,
    const float* __restrict__ W2, const float* __restrict__ b2,
    const float* __restrict__ fcw, const float* __restrict__ fcb,
    float* __restrict__ accg, float* __restrict__ G, int* __restrict__ ucnt)
{
    __shared__ float w[CIN];
    __shared__ float ps[4 * QPB * 5];   // [cg][quad][px], stride-5 bank skew
    __shared__ float acc8[8 * 80];      // [replica][node*5+st], bank-skewed
    __shared__ int done_sh;
    const int tid = threadIdx.x;
    const int b   = blockIdx.x / BPI;
    const int blk = blockIdx.x % BPI;
    const int cg  = tid >> 6;           // channel group == wave id
    const int l   = tid & 63;           // quad lane

    if (tid < CIN) w[tid] = convw[tid];
    for (int i = tid; i < 8 * 80; i += 256) acc8[i] = 0.f;
    __syncthreads();

    const int p = (blk * QPB + l) * 4;
    const float* base = Bfor + (size_t)b * CIN * HWC + (size_t)(cg * 16) * HWC + p;

    float4 s = make_float4(0.f, 0.f, 0.f, 0.f);
    #pragma unroll
    for (int cc = 0; cc < 16; ++cc) {
        const float4 v = *reinterpret_cast<const float4*>(base + (size_t)cc * HWC);
        const float wc = w[cg * 16 + cc];
        s.x = fmaf(v.x, wc, s.x);
        s.y = fmaf(v.y, wc, s.y);
        s.z = fmaf(v.z, wc, s.z);
        s.w = fmaf(v.w, wc, s.w);
    }
    ps[cg * 320 + l * 5 + 0] = s.x;
    ps[cg * 320 + l * 5 + 1] = s.y;
    ps[cg * 320 + l * 5 + 2] = s.z;
    ps[cg * 320 + l * 5 + 3] = s.w;
    __syncthreads();

    if (tid < 64) {
        float r0 = 0.f, r1 = 0.f, r2 = 0.f, r3 = 0.f;
        #pragma unroll
        for (int g = 0; g < 4; ++g) {
            r0 += ps[g * 320 + tid * 5 + 0];
            r1 += ps[g * 320 + tid * 5 + 1];
            r2 += ps[g * 320 + tid * 5 + 2];
            r3 += ps[g * 320 + tid * 5 + 3];
        }
        const int pp = (blk * QPB + tid) * 4;
        const int4 sg = *reinterpret_cast<const int4*>(seg + (size_t)b * HWC + pp);
        const float row  = (float)(pp / WW);   // WW%4==0 -> all 4 px same row
        const float col0 = (float)(pp % WW);
        const int k = tid & 7;                 // replica
        atomicAdd(&acc8[k * 80 + sg.x * 5 + 0], row);
        atomicAdd(&acc8[k * 80 + sg.x * 5 + 1], col0);
        atomicAdd(&acc8[k * 80 + sg.x * 5 + 2], r0);
        atomicAdd(&acc8[k * 80 + sg.x * 5 + 3], 1.f);
        atomicAdd(&acc8[k * 80 + sg.y * 5 + 0], row);
        atomicAdd(&acc8[k * 80 + sg.y * 5 + 1], col0 + 1.f);
        atomicAdd(&acc8[k * 80 + sg.y * 5 + 2], r1);
        atomicAdd(&acc8[k * 80 + sg.y * 5 + 3], 1.f);
        atomicAdd(&acc8[k * 80 + sg.z * 5 + 0], row);
        atomicAdd(&acc8[k * 80 + sg.z * 5 + 1], col0 + 2.f);
        atomicAdd(&acc8[k * 80 + sg.z * 5 + 2], r2);
        atomicAdd(&acc8[k * 80 + sg.z * 5 + 3], 1.f);
        atomicAdd(&acc8[k * 80 + sg.w * 5 + 0], row);
        atomicAdd(&acc8[k * 80 + sg.w * 5 + 1], col0 + 3.f);
        atomicAdd(&acc8[k * 80 + sg.w * 5 + 2], r3);
        atomicAdd(&acc8[k * 80 + sg.w * 5 + 3], 1.f);
    }
    __syncthreads();

    if (tid < 64) {   // 8-replica reduce -> device-coherent accumulate
        float v = 0.f;
        #pragma unroll
        for (int k = 0; k < 8; ++k) v += acc8[k * 80 + (tid >> 2) * 5 + (tid & 3)];
        atomicAdd(&accg[b * 64 + tid], v);
    }
    // value-atomics must COMPLETE before the counter publishes (R12-validated)
    asm volatile("s_waitcnt vmcnt(0)" ::: "memory");
    if (tid == 0) done_sh = (atomicAdd(&ucnt[b], 1) == BPI - 1) ? 1 : 0;
    __syncthreads();
    if (!done_sh) return;

    // ======== graph network for image b (one block per image) ========
    __shared__ float X[NN][4];
    __shared__ float A[NN][NN];
    __shared__ float nrm[NN];
    __shared__ float h1s[NN][32];
    __shared__ float agg[NN][32];
    __shared__ float gpart[2][COUT];

    if (tid < 64)    // coherent read of accumulated stats
        X[tid >> 2][tid & 3] = atomicAdd(&accg[b * 64 + tid], 0.f);
    ((float*)A)[tid] = 0.f;     // 256 entries, 256 threads
    __syncthreads();

    if (tid < NN) {  // raw sums -> features (conv bias folded in)
        const float cnt = X[tid][3];
        const float cs  = fmaxf(cnt, 1.f);
        X[tid][0] = X[tid][0] / cs;
        X[tid][1] = X[tid][1] / cs;
        X[tid][2] = (X[tid][2] + cnt * convb[0]) / cs;
    }
    __syncthreads();

    if (tid < 2) {   // normalize cols 2,3 (mean, std ddof=1)
        const int c = 2 + tid;
        float mu = 0.f;
        for (int i = 0; i < NN; ++i) mu += X[i][c];
        mu *= (1.f / NN);
        float var = 0.f;
        for (int i = 0; i < NN; ++i) { const float d = X[i][c] - mu; var = fmaf(d, d, var); }
        var *= (1.f / (NN - 1));
        const float inv = 1.f / (sqrtf(var) + 1.f);
        for (int i = 0; i < NN; ++i) X[i][c] = (X[i][c] - mu) * inv;
    }
    if (tid >= 64 && tid < 64 + NE) {   // adjacency (idempotent set-to-1)
        const int e = tid - 64;
        const int sE = src[b * NE + e], dE = dst[b * NE + e];
        A[sE][dE] = 1.f;
        A[dE][sE] = 1.f;
    }
    __syncthreads();

    if (tid < NN) {
        float rs = 0.f;
        for (int j = 0; j < NN; ++j) rs += A[tid][j];
        nrm[tid] = 1.f / sqrtf(fmaxf(rs, 1.f));
    }
    __syncthreads();

    if (tid < NN * 4) {   // agg1 (16x4)
        const int i = tid >> 2, k = tid & 3;
        float sA = 0.f;
        for (int j = 0; j < NN; ++j) sA = fmaf(A[i][j] * nrm[j], X[j][k], sA);
        agg[i][k] = sA;
    }
    __syncthreads();

    for (int t = tid; t < NN * 32; t += 256) {   // h1 (16x32)
        const int i = t >> 5, f = t & 31;
        float sA = 0.f;
        #pragma unroll
        for (int k = 0; k < 4; ++k) sA = fmaf(agg[i][k], W1[k * 32 + f], sA);
        h1s[i][f] = fmaxf(fmaf(nrm[i], sA, b1[f]), 0.f);
    }
    __syncthreads();

    for (int t = tid; t < NN * 32; t += 256) {   // agg2 (16x32)
        const int i = t >> 5, k = t & 31;
        float sA = 0.f;
        for (int j = 0; j < NN; ++j) sA = fmaf(A[i][j] * nrm[j], h1s[j][k], sA);
        agg[i][k] = sA;
    }
    __syncthreads();

    {   // h2 + FC, i-range split across 2 half-blocks
        const int f = tid & 127, half = tid >> 7;
        float g = 0.f;
        const float bf = b2[f];
        for (int i = half * 8; i < half * 8 + 8; ++i) {
            float sA = 0.f;
            #pragma unroll
            for (int k = 0; k < 32; ++k) sA = fmaf(agg[i][k], W2[k * COUT + f], sA);
            g = fmaf(fcw[i], fmaxf(fmaf(nrm[i], sA, bf), 0.f), g);
        }
        gpart[half][f] = g;
    }
    __syncthreads();
    // plain store: kernel boundary makes it visible to k_scale
    if (tid < COUT) G[b * COUT + tid] = gpart[0][tid] + gpart[1][tid] + fcb[0];
}

// ---- Kernel 2: pure-stream scale with rolling register prefetch (R9 loop) --
__global__ __launch_bounds__(256) void k_scale(
    const float* __restrict__ Bfon, const float* __restrict__ Gg,
    float* __restrict__ out)
{
    const int b    = blockIdx.x / SBPB;
    const int blkb = blockIdx.x % SBPB;
    const int tid  = threadIdx.x;
    const int w0   = blkb * (JPT * 256);   // contiguous window in [0, PF4)

    __shared__ float Gs[COUT];
    const float4* bf4 = reinterpret_cast<const float4*>(Bfon) + (size_t)b * PF4;
    float4*       ob4 = reinterpret_cast<float4*>(out)        + (size_t)b * PF4;

    float4 r[JPT];
    #pragma unroll
    for (int j = 0; j < PREF; ++j) r[j] = bf4[w0 + j * 256 + tid];

    if (tid < COUT) Gs[tid] = Gg[b * COUT + tid];
    __syncthreads();

    #pragma unroll
    for (int j = 0; j < JPT; ++j) {
        if (j + PREF < JPT) r[j + PREF] = bf4[w0 + (j + PREF) * 256 + tid];
        const int t = w0 + j * 256 + tid;
        const float g = Gs[t / (HW2 / 4)];   // 784 float4 per (b,c) plane
        ob4[t] = make_float4(r[j].x * g, r[j].y * g, r[j].z * g, r[j].w * g);
    }
}

extern "C" void kernel_launch(void* const* d_in, const int* in_sizes, int n_in,
                              void* d_out, int out_size, void* d_ws, size_t ws_size,
                              hipStream_t stream)
{
    const float* Bfor  = (const float*)d_in[0];
    const float* Bfon  = (const float*)d_in[1];
    const int*   seg   = (const int*)d_in[2];
    const int*   src   = (const int*)d_in[3];
    const int*   dst   = (const int*)d_in[4];
    const float* convw = (const float*)d_in[5];
    const float* convb = (const float*)d_in[6];
    const float* W1    = (const float*)d_in[7];
    const float* b1    = (const float*)d_in[8];
    const float* W2    = (const float*)d_in[9];
    const float* b2    = (const float*)d_in[10];
    const float* fcw   = (const float*)d_in[11];
    const float* fcb   = (const float*)d_in[12];

    float* accg = (float*)d_ws;                  // 32*64 floats (zeroed per call)
    float* G    = accg + BB * 64;                // 32*128 floats (fully overwritten)
    int*   ucnt = (int*)(G + BB * COUT);         // 32 ints (zeroed per call)

    hipMemsetAsync(accg, 0, BB * 64 * sizeof(float), stream);
    hipMemsetAsync(ucnt, 0, BB * sizeof(int), stream);
    k_conv_seg<<<BB * BPI, 256, 0, stream>>>(Bfor, seg, convw, src, dst, convb,
                                             W1, b1, W2, b2, fcw, fcb,
                                             accg, G, ucnt);
    k_scale<<<BB * SBPB, 256, 0, stream>>>(Bfon, G, (float*)d_out);
}